// Round 2
// baseline (219.297 us; speedup 1.0000x reference)
//
#include <hip/hip_runtime.h>
#include <hip/hip_bf16.h>
#include <stdint.h>

#define IN_F 128
#define EDGE_F 6
#define TILE_E 4096      // hist/scatter tile; K1 hist blocks and K2 blocks MUST share this mapping
#define NBIN_PAD 256     // coarse bins = dst>>8 (n_nodes <= 65536 assumed; N=50000 -> 196 bins)
#define SPLIT 8          // fine_agg blocks per coarse bucket (32 dsts each)
#define IDXCAP 1280      // per-slice LDS index capacity (slice mean 512, sigma ~23 -> +34 sigma)

using bf16x8 = __attribute__((ext_vector_type(8))) short;  // 8 bf16 = 4 VGPRs
using f32x4  = __attribute__((ext_vector_type(4))) float;

__device__ __forceinline__ float bf2f(unsigned short u) {
    return __uint_as_float(((unsigned int)u) << 16);
}
__device__ __forceinline__ unsigned short f2bfbits(float f) {
    __hip_bfloat16 h = __float2bfloat16(f);  // RNE
    return *reinterpret_cast<unsigned short*>(&h);
}
__device__ __forceinline__ unsigned int packbf(float a, float b) {
    return ((unsigned int)f2bfbits(b) << 16) | (unsigned int)f2bfbits(a);
}

// ---- K1: payload pack + nf cast + LDS-privatized coarse histogram + weight pack ----
// ZERO scattered global atomics (the old 800K atomicAdd stream was 44us of pure
// TCC-RMW dead time). Blocks 0..nblk_e-1 additionally count a 4096-edge tile
// into a 196-bin LDS histogram (cb = dst>>8) and write one 512B ushort row of
// the partial matrix. Block eb does the weight pack.
__global__ __launch_bounds__(256) void pack_hist_cast(
        const int* __restrict__ eidx, const float* __restrict__ ef,
        uint4* __restrict__ efp, unsigned short* __restrict__ pmat,
        int n_edges, int nblk_e, int n_cast, int eb,
        const float* __restrict__ nf, unsigned short* __restrict__ nfb,
        const float* __restrict__ W, const float* __restrict__ b,
        const float* __restrict__ We, const float* __restrict__ be,
        unsigned short* __restrict__ Wpack, float* __restrict__ W2pack) {
    const int tid = threadIdx.x;
    const int blk = blockIdx.x;
    __shared__ int hist[NBIN_PAD];

    if (blk == eb) {
        // Wpack: idx=((kb*8+ft)*64+lane)*8+j -> bf16(W[kb*32+(lane>>4)*8+j][ft*16+(lane&15)])
        for (int idx = tid; idx < 16384; idx += 256) {
            int j = idx & 7, lane = (idx >> 3) & 63, ft = (idx >> 9) & 7, kb = idx >> 12;
            int k = kb * 32 + (lane >> 4) * 8 + j;
            int f = ft * 16 + (lane & 15);
            Wpack[idx] = f2bfbits(W[k * 128 + f]);
        }
        for (int idx = tid; idx < 1024; idx += 256) {
            int j = idx >> 7, f = idx & 127;
            float w = 0.f;
            if (j < 6)       w = We[j * 128 + f];
            else if (j == 6) w = b[f] + be[f];
            W2pack[idx] = w;
        }
    } else {
        const bool hb = (blk < nblk_e);
        if (hb) {
            hist[tid] = 0;
            __syncthreads();
        }
        // pack tile: 256 edges/block, e-order, coalesced. src,dst < 65536 so
        // dst rides in the high half of q.x; downstream never re-reads eidx.
        const int t = blk * 256 + tid;
        if (t < n_edges) {
            const int2 pr = reinterpret_cast<const int2*>(eidx)[t];  // (src, dst)
            const float2* efs = reinterpret_cast<const float2*>(ef + (size_t)t * EDGE_F);
            const float2 f0 = efs[0], f1 = efs[1], f2 = efs[2];
            uint4 q;
            q.x = (unsigned int)pr.x | ((unsigned int)pr.y << 16);
            q.y = packbf(f0.x, f0.y);
            q.z = packbf(f1.x, f1.y);
            q.w = packbf(f2.x, f2.y);
            efp[t] = q;
        }
        // coarse histogram tile (LDS atomics only)
        if (hb) {
            const int e0 = blk * TILE_E;
#pragma unroll
            for (int i = 0; i < TILE_E / 256; ++i) {
                const int e = e0 + i * 256 + tid;
                if (e < n_edges) {
                    const int dst = reinterpret_cast<const int2*>(eidx)[e].y;
                    atomicAdd(&hist[dst >> 8], 1);
                }
            }
            __syncthreads();
            pmat[(size_t)blk * NBIN_PAD + tid] = (unsigned short)hist[tid];
        }
    }
    // nf -> bf16 cast rides along (grid-stride; exactly 1 unit/thread at E=800K)
    const int t = blk * 256 + tid;
    const int stride = gridDim.x * 256;
    for (int i = t; i < n_cast; i += stride) {
        const float4 lo = reinterpret_cast<const float4*>(nf)[2 * i];
        const float4 hi = reinterpret_cast<const float4*>(nf)[2 * i + 1];
        uint4 o;
        o.x = packbf(lo.x, lo.y); o.y = packbf(lo.z, lo.w);
        o.z = packbf(hi.x, hi.y); o.w = packbf(hi.z, hi.w);
        reinterpret_cast<uint4*>(nfb)[i] = o;
    }
}

// ---- K2: coarse scatter into dst>>8 buckets. No global atomics. ----
// Each block reconstructs its per-bin start cursor from the partial matrix
// (100 KB, L2-broadcast): cursor[c] = base[c] + sum_{b'<blk} pmat[b'][c].
// Same tile mapping as K1's hist blocks -> counts match scatters exactly ->
// slots form a bijection. Writes have ~21-edge (336B) run locality.
__global__ __launch_bounds__(256) void coarse_scatter(
        const uint4* __restrict__ efp, const unsigned short* __restrict__ pmat,
        uint4* __restrict__ rec_c, int* __restrict__ gbase,
        int n_edges, int nblk_e, int nbin) {
    const int tid = threadIdx.x;
    const int blk = blockIdx.x;
    __shared__ int cur[NBIN_PAD];
    __shared__ int sc[NBIN_PAD];
    int tot = 0, pre = 0;
#pragma unroll 4
    for (int bb = 0; bb < nblk_e; ++bb) {
        const int v = pmat[(size_t)bb * NBIN_PAD + tid];
        tot += v;
        pre += (bb < blk) ? v : 0;
    }
    sc[tid] = tot;
    __syncthreads();
    for (int off = 1; off < 256; off <<= 1) {  // inclusive scan of totals
        int t2 = (tid >= off) ? sc[tid - off] : 0;
        __syncthreads();
        sc[tid] += t2;
        __syncthreads();
    }
    const int excl = sc[tid] - tot;            // base[tid]
    cur[tid] = excl + pre;
    if (blk == 0 && tid <= nbin) gbase[tid] = excl;  // gbase[nbin] == n_edges
    __syncthreads();
    const int e0 = blk * TILE_E;
#pragma unroll
    for (int i = 0; i < TILE_E / 256; ++i) {
        const int e = e0 + i * 256 + tid;
        if (e < n_edges) {
            const uint4 q = efp[e];
            const int cb = q.x >> 24;          // dst>>8 (dst = q.x>>16, 16-bit)
            const int pos = atomicAdd(&cur[cb], 1);
            rec_c[pos] = q;
        }
    }
}

// ---- K3: fused fine-rank + aggregate. Replaces fine_rank + aggregate_bf16. ----
// SPLIT=8 blocks per 256-node coarse bucket (grid 1568, ~6 blk/CU, ~24
// waves/CU -> MORE outstanding gathers than the old 18-wave aggregate). Each
// block scans the bucket's qx words (L1/L2-hot, ~64KB window), builds a
// compact LDS index list for ITS 32-dst slice, then runs the proven 8-deep
// wave-uniform-scalar gather pipeline per dst. No sorted rec, no rowptr, no
// rank buffers: the permutation lives and dies in 2.6KB of LDS. deg comes
// from the LDS histogram. Full-scan fallback if the slice overflows IDXCAP
// (>=30 sigma away for this input -- never taken, correctness-only).
__global__ __launch_bounds__(256) void fine_agg(
        const uint4* __restrict__ rec_c, const int* __restrict__ gbase,
        const unsigned short* __restrict__ nfb,
        unsigned short* __restrict__ S, unsigned short* __restrict__ E8,
        int n_nodes) {
    const int tid = threadIdx.x;
    const int c = blockIdx.x / SPLIT;
    const int part = blockIdx.x % SPLIT;
    const int rbase = gbase[c], rend = gbase[c + 1];
    const int sz = rend - rbase;
    __shared__ int scnt[32];
    __shared__ int spos[32];
    __shared__ int sok;
    __shared__ unsigned short sidx[IDXCAP];
    if (tid < 32) scnt[tid] = 0;
    __syncthreads();
    // pass 1: count records belonging to this block's 32-dst slice
    for (int i = tid; i < sz; i += 256) {
        const unsigned int qx =
            reinterpret_cast<const unsigned int*>(rec_c)[(size_t)(rbase + i) * 4];
        const int d = (qx >> 16) & 255;
        if ((d >> 5) == part) atomicAdd(&scnt[d & 31], 1);
    }
    __syncthreads();
    if (tid == 0) {
        int run = 0;
        for (int j = 0; j < 32; ++j) { spos[j] = run; run += scnt[j]; }
        sok = (run <= IDXCAP && sz <= 65535) ? 1 : 0;
    }
    __syncthreads();
    const int ok = sok;
    if (ok) {
        // pass 2: build compact index list (any within-dst order is valid)
        for (int i = tid; i < sz; i += 256) {
            const unsigned int qx =
                reinterpret_cast<const unsigned int*>(rec_c)[(size_t)(rbase + i) * 4];
            const int d = (qx >> 16) & 255;
            if ((d >> 5) == part) {
                const int r = atomicAdd(&spos[d & 31], 1);
                sidx[r] = (unsigned short)i;
            }
        }
        __syncthreads();
    }
    const int lane = tid & 63;
    const int wv = tid >> 6;
#pragma unroll 1
    for (int k = 0; k < 8; ++k) {
        const int dl = part * 32 + wv * 8 + k;   // dst & 255
        const int n = c * 256 + dl;
        if (n >= n_nodes) continue;
        float ax = 0.f, ay = 0.f;
        float e0 = 0.f, e1 = 0.f, e2 = 0.f, e3 = 0.f, e4 = 0.f, e5 = 0.f;
        int deg = 0;
        if (ok) {
            const int cnt = scnt[dl & 31];
            const int start = spos[dl & 31] - cnt;   // spos holds end after pass 2
            deg = cnt;
            int j = 0;
            for (; j + 7 < cnt; j += 8) {  // 8 gathers in flight
                int ei[8]; uint4 q[8]; unsigned int u[8];
#pragma unroll
                for (int t2 = 0; t2 < 8; ++t2)
                    ei[t2] = __builtin_amdgcn_readfirstlane(rbase + (int)sidx[start + j + t2]);
#pragma unroll
                for (int t2 = 0; t2 < 8; ++t2) q[t2] = rec_c[ei[t2]];   // scalar, L1-hot
#pragma unroll
                for (int t2 = 0; t2 < 8; ++t2)
                    u[t2] = reinterpret_cast<const unsigned int*>(
                        nfb + (size_t)(q[t2].x & 0xFFFFu) * IN_F)[lane];
#pragma unroll
                for (int t2 = 0; t2 < 8; ++t2) {
                    ax += bf2f((unsigned short)u[t2]);
                    ay += bf2f((unsigned short)(u[t2] >> 16));
                    e0 += bf2f((unsigned short)q[t2].y);
                    e1 += bf2f((unsigned short)(q[t2].y >> 16));
                    e2 += bf2f((unsigned short)q[t2].z);
                    e3 += bf2f((unsigned short)(q[t2].z >> 16));
                    e4 += bf2f((unsigned short)q[t2].w);
                    e5 += bf2f((unsigned short)(q[t2].w >> 16));
                }
            }
            for (; j + 3 < cnt; j += 4) {
                int ei[4]; uint4 q[4]; unsigned int u[4];
#pragma unroll
                for (int t2 = 0; t2 < 4; ++t2)
                    ei[t2] = __builtin_amdgcn_readfirstlane(rbase + (int)sidx[start + j + t2]);
#pragma unroll
                for (int t2 = 0; t2 < 4; ++t2) q[t2] = rec_c[ei[t2]];
#pragma unroll
                for (int t2 = 0; t2 < 4; ++t2)
                    u[t2] = reinterpret_cast<const unsigned int*>(
                        nfb + (size_t)(q[t2].x & 0xFFFFu) * IN_F)[lane];
#pragma unroll
                for (int t2 = 0; t2 < 4; ++t2) {
                    ax += bf2f((unsigned short)u[t2]);
                    ay += bf2f((unsigned short)(u[t2] >> 16));
                    e0 += bf2f((unsigned short)q[t2].y);
                    e1 += bf2f((unsigned short)(q[t2].y >> 16));
                    e2 += bf2f((unsigned short)q[t2].z);
                    e3 += bf2f((unsigned short)(q[t2].z >> 16));
                    e4 += bf2f((unsigned short)q[t2].w);
                    e5 += bf2f((unsigned short)(q[t2].w >> 16));
                }
            }
            for (; j < cnt; ++j) {
                const int e = __builtin_amdgcn_readfirstlane(rbase + (int)sidx[start + j]);
                const uint4 q0 = rec_c[e];
                const unsigned int u0 = reinterpret_cast<const unsigned int*>(
                    nfb + (size_t)(q0.x & 0xFFFFu) * IN_F)[lane];
                ax += bf2f((unsigned short)u0); ay += bf2f((unsigned short)(u0 >> 16));
                e0 += bf2f((unsigned short)q0.y); e1 += bf2f((unsigned short)(q0.y >> 16));
                e2 += bf2f((unsigned short)q0.z); e3 += bf2f((unsigned short)(q0.z >> 16));
                e4 += bf2f((unsigned short)q0.w); e5 += bf2f((unsigned short)(q0.w >> 16));
            }
        } else {
            // fallback: full bucket scan (correctness-only, never taken here)
            for (int i2 = 0; i2 < sz; ++i2) {
                const int e = __builtin_amdgcn_readfirstlane(rbase + i2);
                const uint4 q0 = rec_c[e];
                if ((int)((q0.x >> 16) & 255) == dl) {
                    const unsigned int u0 = reinterpret_cast<const unsigned int*>(
                        nfb + (size_t)(q0.x & 0xFFFFu) * IN_F)[lane];
                    ax += bf2f((unsigned short)u0); ay += bf2f((unsigned short)(u0 >> 16));
                    e0 += bf2f((unsigned short)q0.y); e1 += bf2f((unsigned short)(q0.y >> 16));
                    e2 += bf2f((unsigned short)q0.z); e3 += bf2f((unsigned short)(q0.z >> 16));
                    e4 += bf2f((unsigned short)q0.w); e5 += bf2f((unsigned short)(q0.w >> 16));
                    ++deg;
                }
            }
        }
        unsigned short* row = S + (size_t)n * IN_F;
        reinterpret_cast<unsigned int*>(row)[lane] = packbf(ax, ay);
        if (lane == 0) {
            uint4 qq;
            qq.x = packbf(e0, e1);
            qq.y = packbf(e2, e3);
            qq.z = packbf(e4, e5);
            qq.w = packbf((float)deg, 0.f);     // deg exact in bf16 (small)
            *reinterpret_cast<uint4*>(E8 + (size_t)n * 8) = qq;
        }
    }
}

// ---- K4: MFMA GEMM  out = relu( S[N,128]bf16 @ W[128,128]bf16 + E-term ) ----
__global__ __launch_bounds__(256) void gemm_mfma(
        const unsigned short* __restrict__ S, const unsigned short* __restrict__ E8,
        const unsigned short* __restrict__ Wpack, const float* __restrict__ W2pack,
        float* __restrict__ out, int n_nodes) {
    __shared__ __align__(16) short Wl[16384];   // 32 KB, B-fragment layout
    __shared__ float W2l[1024];                 // 4 KB
    const int tid = threadIdx.x;
    for (int i = tid; i < 2048; i += 256)
        reinterpret_cast<uint4*>(Wl)[i] = reinterpret_cast<const uint4*>(Wpack)[i];
    for (int i = tid; i < 1024; i += 256) W2l[i] = W2pack[i];

    const int wv = tid >> 6, lane = tid & 63;
    const int m = lane & 15, quad = lane >> 4;
    const int n0 = blockIdx.x * 64 + wv * 16;

    const int arow = min(n0 + m, n_nodes - 1);
    const unsigned short* ap = S + (size_t)arow * IN_F + quad * 8;
    bf16x8 a[4];
#pragma unroll
    for (int kb = 0; kb < 4; ++kb)
        a[kb] = *reinterpret_cast<const bf16x8*>(ap + kb * 32);

    __syncthreads();

    f32x4 acc[8];
#pragma unroll
    for (int ft = 0; ft < 8; ++ft) acc[ft] = (f32x4){0.f, 0.f, 0.f, 0.f};

#pragma unroll
    for (int kb = 0; kb < 4; ++kb) {
#pragma unroll
        for (int ft = 0; ft < 8; ++ft) {
            const bf16x8 bfrag =
                reinterpret_cast<const bf16x8*>(Wl)[(kb * 8 + ft) * 64 + lane];
            acc[ft] = __builtin_amdgcn_mfma_f32_16x16x32_bf16(a[kb], bfrag, acc[ft], 0, 0, 0);
        }
    }

    // Epilogue. C/D layout: col=lane&15, row=quad*4+reg.
    float e[4][7];
#pragma unroll
    for (int r = 0; r < 4; ++r) {
        const int n = min(n0 + quad * 4 + r, n_nodes - 1);
        const uint4 q = *reinterpret_cast<const uint4*>(E8 + (size_t)n * 8);
        e[r][0] = bf2f((unsigned short)q.x); e[r][1] = bf2f((unsigned short)(q.x >> 16));
        e[r][2] = bf2f((unsigned short)q.y); e[r][3] = bf2f((unsigned short)(q.y >> 16));
        e[r][4] = bf2f((unsigned short)q.z); e[r][5] = bf2f((unsigned short)(q.z >> 16));
        e[r][6] = bf2f((unsigned short)q.w);  // deg
    }
#pragma unroll
    for (int ft = 0; ft < 8; ++ft) {
        const int f = ft * 16 + m;
        float w2[7];
#pragma unroll
        for (int j = 0; j < 7; ++j) w2[j] = W2l[j * 128 + f];
#pragma unroll
        for (int r = 0; r < 4; ++r) {
            const int n = n0 + quad * 4 + r;
            if (n < n_nodes) {
                float v = acc[ft][r];
#pragma unroll
                for (int j = 0; j < 7; ++j) v += e[r][j] * w2[j];
                out[(size_t)n * 128 + f] = fmaxf(v, 0.f);
            }
        }
    }
}

extern "C" void kernel_launch(void* const* d_in, const int* in_sizes, int n_in,
                              void* d_out, int out_size, void* d_ws, size_t ws_size,
                              hipStream_t stream) {
    const float* nf = (const float*)d_in[0];  // fp32 (N,128)
    const int* eidx = (const int*)d_in[1];    // int32 (E,2)
    const float* ef = (const float*)d_in[2];  // fp32 (E,6)
    const float* W  = (const float*)d_in[3];  // fp32 (128,128)
    const float* b  = (const float*)d_in[4];  // fp32 (128,)
    const float* We = (const float*)d_in[5];  // fp32 (6,128)
    const float* be = (const float*)d_in[6];  // fp32 (128,)
    float* out = (float*)d_out;               // fp32 (N,128)

    const int n_nodes = in_sizes[0] / IN_F;
    const int n_edges = in_sizes[1] / 2;

    const int eb = (n_edges + 255) / 256;                 // 3125 pack blocks
    const int nblk_e = (n_edges + TILE_E - 1) / TILE_E;   // 196 hist/scatter blocks
    const int nbin = (n_nodes + 255) >> 8;                // 196 coarse buckets
    const int n_cast = n_nodes * (IN_F / 8);

    // ws (~40 MB): efp | rec_c (16B*E each) | S | E8 | Wpack | W2pack
    //   | pmat (nblk_e*256 ushort) | gbase (260 int) | nfb
    // rec / rowptr / rank are GONE (fine rank lives in fine_agg's LDS).
    uint4* efp   = (uint4*)d_ws;
    uint4* rec_c = efp + n_edges;
    unsigned short* S = (unsigned short*)(rec_c + n_edges);
    unsigned short* E8 = S + (size_t)n_nodes * IN_F;
    unsigned short* Wpack = E8 + (size_t)n_nodes * 8;
    float* W2pack = (float*)(Wpack + 16384);
    unsigned short* pmat = (unsigned short*)(W2pack + 1024);
    int* gbase = (int*)(pmat + (size_t)nblk_e * NBIN_PAD);
    unsigned short* nfb = (unsigned short*)(gbase + 260);

    // No memset needed: pmat rows fully written, all cursors derived in-LDS.
    pack_hist_cast<<<eb + 1, 256, 0, stream>>>(eidx, ef, efp, pmat,
                                               n_edges, nblk_e, n_cast, eb,
                                               nf, nfb, W, b, We, be, Wpack, W2pack);
    coarse_scatter<<<nblk_e, 256, 0, stream>>>(efp, pmat, rec_c, gbase,
                                               n_edges, nblk_e, nbin);
    fine_agg<<<nbin * SPLIT, 256, 0, stream>>>(rec_c, gbase, nfb, S, E8, n_nodes);
    gemm_mfma<<<(n_nodes + 63) / 64, 256, 0, stream>>>(S, E8, Wpack, W2pack, out, n_nodes);
}